// Round 21
// baseline (32.435 us; speedup 1.0000x reference)
//
#include <hip/hip_runtime.h>

// CRF NLL forward, B=8192, L=512, T=6 (4 real states + START/STOP).
// 64-lane wave = 2 batches x 32 lanes. Lane (g,c) covers steps [16c,16c+16)
// of batch g, computed as TWO independent interleaved 8-step half-chains
// (P_lo: steps 0-7, P_hi: steps 8-15; scaled-probability domain, pow2
// renorm, exponents in ints) merged by one 4x4 product P = P_hi * P_lo.
// Rationale (R21): latency-bound at the (256,4) tier; 5/6/8-wave tiers all
// spill (natural VGPR>102), but the 4-wave tier allows 128 VGPR and we use
// ~110 -> spend the headroom on 2x chain-level ILP instead of impossible TLP.
// ALL 24 feat + 4 tag loads issued up front (MLP). Combine: 4 ordered
// __shfl_down rounds width 32 (renorm after k=2,8) + final k=16 rank-1
// mat-vec. Gold fused per-lane (order-free), width-32 reduced.

#define BB 8192
#define LL 512
#define LN2F 0.69314718055994530942f

__device__ __forceinline__ float uniformf(float x) {
    return __uint_as_float(__builtin_amdgcn_readfirstlane(__float_as_uint(x)));
}

#define RENORM16(P, MEX)                                                \
  do {                                                                  \
    float m_ = fmaxf(P[0], P[1]);                                       \
    _Pragma("unroll") for (int z_ = 2; z_ < 16; ++z_) m_ = fmaxf(m_, P[z_]); \
    const int ee_ = (int)((__float_as_uint(m_) >> 23) & 255) - 127;     \
    const float sc_ = __uint_as_float((unsigned)(127 - ee_) << 23);     \
    _Pragma("unroll") for (int z_ = 0; z_ < 16; ++z_) P[z_] *= sc_;     \
    MEX += ee_;                                                         \
  } while (0)

// One step on matrix PM at absolute index ABS (masked), fused gold.
#define STEPM(PM, ABS, F0v, F1v, F2v, F3v, TG, PV)                      \
  do {                                                                  \
    const bool act_ = (ABS) < len;                                      \
    const float f0_=(F0v), f1_=(F1v), f2_=(F2v), f3_=(F3v);             \
    const float fe0_=__expf(f0_), fe1_=__expf(f1_);                     \
    const float fe2_=__expf(f2_), fe3_=__expf(f3_);                     \
    _Pragma("unroll")                                                   \
    for (int j = 0; j < 4; ++j) {                                       \
      const float c0_=PM[0*4+j], c1_=PM[1*4+j], c2_=PM[2*4+j], c3_=PM[3*4+j]; \
      const float t0_ = fmaf(E[0], c0_, fmaf(E[1], c1_, fmaf(E[2], c2_, E[3] *c3_))); \
      const float t1_ = fmaf(E[4], c0_, fmaf(E[5], c1_, fmaf(E[6], c2_, E[7] *c3_))); \
      const float t2_ = fmaf(E[8], c0_, fmaf(E[9], c1_, fmaf(E[10],c2_, E[11]*c3_))); \
      const float t3_ = fmaf(E[12],c0_, fmaf(E[13],c1_, fmaf(E[14],c2_, E[15]*c3_))); \
      PM[0*4+j] = act_ ? fe0_*t0_ : PM[0*4+j];                          \
      PM[1*4+j] = act_ ? fe1_*t1_ : PM[1*4+j];                          \
      PM[2*4+j] = act_ ? fe2_*t2_ : PM[2*4+j];                          \
      PM[3*4+j] = act_ ? fe3_*t3_ : PM[3*4+j];                          \
    }                                                                   \
    const float lut_ = sT[(TG) * 6 + (PV)];                             \
    const float em_  = ((TG) & 2) ? (((TG) & 1) ? f3_ : f2_)            \
                                  : (((TG) & 1) ? f1_ : f0_);           \
    gold += act_ ? (lut_ + em_) : 0.f;                                  \
  } while (0)

#define TGAT(S)  ((int)((tpk >> (2*(S))) & 3u))
#define SE(PM,S) STEPM(PM, base+(S), F0[(S)/2].x, F0[(S)/2].y, F0[(S)/2].z, F0[(S)/2].w, TGAT(S), TGAT((S)-1))
#define SO(PM,S) STEPM(PM, base+(S), F1[(S)/2].x, F1[(S)/2].y, F2[(S)/2].x, F2[(S)/2].y, TGAT(S), TGAT((S)-1))

__global__ __launch_bounds__(256, 4) void crf_tree(
    const float* __restrict__ feats,
    const float* __restrict__ trans,
    const int*   __restrict__ tags,
    const int*   __restrict__ lens,
    float* __restrict__ partials)
{
    __shared__ float sT[36];

    const int tid  = threadIdx.x;
    const int lane = tid & 63;
    const int wv   = tid >> 6;
    const int g    = lane >> 5;        // batch sub-index within wave (0..1)
    const int c    = lane & 31;        // segment index (0..31), 16 steps each
    const int b    = blockIdx.x * 8 + wv * 2 + g;

    if (tid < 36) sT[tid] = trans[tid];
    __syncthreads();

    // wave-uniform transition constants (SGPR via readfirstlane)
    float E[16], e4[4], e5[4];
    #pragma unroll
    for (int i = 0; i < 16; ++i)
        E[i] = uniformf(__expf(sT[(i >> 2) * 6 + (i & 3)]));
    #pragma unroll
    for (int i = 0; i < 4; ++i) {
        e4[i] = uniformf(__expf(sT[i * 6 + 4]));   // exp(trans[i][START])
        e5[i] = uniformf(__expf(sT[30 + i]));      // exp(trans[STOP][i])
    }

    const int len  = lens[b];
    const int base = c * 16;
    const bool seg0 = (c == 0);

    const float* fp  = feats + (size_t)b * (LL * 6) + (size_t)base * 6;
    const int*   tbp = tags  + (size_t)b * LL + base;
    const int pv0 = seg0 ? 4 : (tbp[-1] & 3);

    // ---- ALL loads issued up front (24 feat + 4 tag loads in flight) ----
    float4 F0[8]; float2 F1[8], F2[8];
    #pragma unroll
    for (int p = 0; p < 8; ++p) {
        const float* q = fp + p * 12;
        F0[p] = *(const float4*)(q);
        F1[p] = *(const float2*)(q + 6);
        F2[p] = *(const float2*)(q + 8);
    }
    unsigned tpk = 0;                      // 16 tags packed 2b each
    #pragma unroll
    for (int q = 0; q < 4; ++q) {
        const int4 t = *(const int4*)(tbp + q * 4);
        tpk |= (unsigned)(t.x & 3) << (2*(q*4+0));
        tpk |= (unsigned)(t.y & 3) << (2*(q*4+1));
        tpk |= (unsigned)(t.z & 3) << (2*(q*4+2));
        tpk |= (unsigned)(t.w & 3) << (2*(q*4+3));
    }

    float PL[16], PH[16];
    #pragma unroll
    for (int z = 0; z < 16; ++z) {
        PL[z] = (z % 5 == 0) ? 1.f : 0.f;
        PH[z] = (z % 5 == 0) ? 1.f : 0.f;
    }
    int   mexL = 0, mexH = 0;
    float gold = 0.f;

    // ---- lo chain step 0 specialized (PL=I; seg0 folds e4/START) ----
    {
        const bool act_ = base < len;
        const float f0_=F0[0].x, f1_=F0[0].y, f2_=F0[0].z, f3_=F0[0].w;
        const float fe0_=__expf(f0_), fe1_=__expf(f1_);
        const float fe2_=__expf(f2_), fe3_=__expf(f3_);
        #pragma unroll
        for (int j = 0; j < 4; ++j) {
            const float u0 = seg0 ? e4[0] : E[0*4+j];
            const float u1 = seg0 ? e4[1] : E[1*4+j];
            const float u2 = seg0 ? e4[2] : E[2*4+j];
            const float u3 = seg0 ? e4[3] : E[3*4+j];
            PL[0*4+j] = act_ ? fe0_*u0 : PL[0*4+j];
            PL[1*4+j] = act_ ? fe1_*u1 : PL[1*4+j];
            PL[2*4+j] = act_ ? fe2_*u2 : PL[2*4+j];
            PL[3*4+j] = act_ ? fe3_*u3 : PL[3*4+j];
        }
        const int t0 = TGAT(0);
        const float lut_ = sT[t0 * 6 + pv0];
        const float em_  = (t0 & 2) ? ((t0 & 1) ? f3_ : f2_)
                                    : ((t0 & 1) ? f1_ : f0_);
        gold += act_ ? (lut_ + em_) : 0.f;
    }
    // ---- hi chain step 8 specialized (PH=I -> diag(fe)*E, 16 muls) ----
    {
        const bool act_ = (base + 8) < len;
        const float f0_=F0[4].x, f1_=F0[4].y, f2_=F0[4].z, f3_=F0[4].w;
        const float fe0_=__expf(f0_), fe1_=__expf(f1_);
        const float fe2_=__expf(f2_), fe3_=__expf(f3_);
        #pragma unroll
        for (int j = 0; j < 4; ++j) {
            PH[0*4+j] = act_ ? fe0_*E[0*4+j] : PH[0*4+j];
            PH[1*4+j] = act_ ? fe1_*E[1*4+j] : PH[1*4+j];
            PH[2*4+j] = act_ ? fe2_*E[2*4+j] : PH[2*4+j];
            PH[3*4+j] = act_ ? fe3_*E[3*4+j] : PH[3*4+j];
        }
        const int t8 = TGAT(8);
        const float lut_ = sT[t8 * 6 + TGAT(7)];
        const float em_  = (t8 & 2) ? ((t8 & 1) ? f3_ : f2_)
                                    : ((t8 & 1) ? f1_ : f0_);
        gold += act_ ? (lut_ + em_) : 0.f;
    }

    // ---- interleaved dual chains: 2x ILP on the exp->FMA critical path ----
    SO(PL,1);  SO(PH,9);
    SE(PL,2);  SE(PH,10);
    SO(PL,3);  SO(PH,11);
    RENORM16(PL, mexL);  RENORM16(PH, mexH);
    SE(PL,4);  SE(PH,12);
    SO(PL,5);  SO(PH,13);
    SE(PL,6);  SE(PH,14);
    SO(PL,7);  SO(PH,15);
    RENORM16(PL, mexL);  RENORM16(PH, mexH);

    // ---- merge: P = P_hi * P_lo (later x earlier) ----
    int mex = mexL + mexH;
    {
        float N[16];
        #pragma unroll
        for (int i = 0; i < 4; ++i)
            #pragma unroll
            for (int j = 0; j < 4; ++j)
                N[i*4+j] = fmaf(PH[i*4+0], PL[0*4+j], fmaf(PH[i*4+1], PL[1*4+j],
                           fmaf(PH[i*4+2], PL[2*4+j], PH[i*4+3] * PL[3*4+j])));
        #pragma unroll
        for (int z = 0; z < 16; ++z) PL[z] = N[z];
        RENORM16(PL, mex);
    }

    // terminal gold: lane owning step len-1 adds trans[STOP][last_tag]
    {
        const unsigned dl = (unsigned)(len - 1 - base);
        if (dl < 16u) gold += sT[30 + (int)((tpk >> (2*dl)) & 3u)];
    }

    // ---- ordered combine width 32: P <- P_{c+k} * P_c, k=1,2,4,8 ----
    #pragma unroll
    for (int k = 1; k <= 8; k <<= 1) {
        float Q[16];
        #pragma unroll
        for (int z = 0; z < 16; ++z) Q[z] = __shfl_down(PL[z], k, 32);
        const int mq = __shfl_down(mex, k, 32);
        float N[16];
        #pragma unroll
        for (int i = 0; i < 4; ++i)
            #pragma unroll
            for (int j = 0; j < 4; ++j)
                N[i*4+j] = fmaf(Q[i*4+0], PL[0*4+j], fmaf(Q[i*4+1], PL[1*4+j],
                           fmaf(Q[i*4+2], PL[2*4+j], Q[i*4+3] * PL[3*4+j])));
        #pragma unroll
        for (int z = 0; z < 16; ++z) PL[z] = N[z];
        mex += mq;
        if (k == 2 || k == 8) RENORM16(PL, mex);
    }

    // ---- final k=16: rank-1 -> mat-vec (alpha = column 0) ----
    float al0, al1, al2, al3;
    {
        float Q[16];
        #pragma unroll
        for (int z = 0; z < 16; ++z) Q[z] = __shfl_down(PL[z], 16, 32);
        const int mq = __shfl_down(mex, 16, 32);
        al0 = fmaf(Q[0], PL[0], fmaf(Q[1], PL[4], fmaf(Q[2], PL[8], Q[3] *PL[12])));
        al1 = fmaf(Q[4], PL[0], fmaf(Q[5], PL[4], fmaf(Q[6], PL[8], Q[7] *PL[12])));
        al2 = fmaf(Q[8], PL[0], fmaf(Q[9], PL[4], fmaf(Q[10],PL[8], Q[11]*PL[12])));
        al3 = fmaf(Q[12],PL[0], fmaf(Q[13],PL[4], fmaf(Q[14],PL[8], Q[15]*PL[12])));
        mex += mq;
    }

    // gold: sum across the 32-lane group
    #pragma unroll
    for (int k = 1; k <= 16; k <<= 1)
        gold += __shfl_xor(gold, k, 32);

    const float dot = fmaf(e5[0], al0, fmaf(e5[1], al1,
                      fmaf(e5[2], al2, e5[3] * al3)));
    const float logz = fmaf((float)mex, LN2F, __logf(dot));
    if (c == 0)
        partials[b] = logz - gold;
}

__global__ __launch_bounds__(256) void k_reduce(const float* __restrict__ partials,
                                               float* __restrict__ out)
{
    __shared__ float sh[256];
    const int t = threadIdx.x;
    float s = 0.f;
    #pragma unroll
    for (int j = 0; j < 32; ++j) s += partials[t + 256 * j];
    sh[t] = s;
    __syncthreads();
    #pragma unroll
    for (int d = 128; d > 0; d >>= 1) {
        if (t < d) sh[t] += sh[t + d];
        __syncthreads();
    }
    if (t == 0) out[0] = sh[0] * (1.0f / 8192.0f);
}

extern "C" void kernel_launch(void* const* d_in, const int* in_sizes, int n_in,
                              void* d_out, int out_size, void* d_ws, size_t ws_size,
                              hipStream_t stream) {
    const float* feats = (const float*)d_in[0];
    const float* trans = (const float*)d_in[1];
    const int*   tags  = (const int*)d_in[2];
    const int*   lens  = (const int*)d_in[3];
    float* out = (float*)d_out;
    float* partials = (float*)d_ws;        // 8192 floats

    crf_tree<<<BB / 8, 256, 0, stream>>>(feats, trans, tags, lens, partials);
    k_reduce<<<1, 256, 0, stream>>>(partials, out);
}